// Round 3
// baseline (156.596 us; speedup 1.0000x reference)
//
#include <hip/hip_runtime.h>
#include <hip/hip_bf16.h>

typedef __attribute__((ext_vector_type(4))) float f32x4;
typedef __attribute__((ext_vector_type(8))) short bf16x8;

#define H 1024        // hidden / K
#define NTOT 1280     // nq*64 + nkv*64*2
#define BM 256
#define BN 256
#define BK 64
#define NKT (H / BK)  // 16 K-tiles

static __device__ __forceinline__ unsigned short f2bf(float f) {
    __hip_bfloat16 b = __float2bfloat16(f);
    return __builtin_bit_cast(unsigned short, b);
}

#define GLOAD_LDS16(g, l)                                                     \
    __builtin_amdgcn_global_load_lds(                                         \
        (const __attribute__((address_space(1))) void*)(g),                   \
        (__attribute__((address_space(3))) void*)(l), 16, 0, 0)

// ---------------------------------------------------------------------------
// Kernel 1: RMSNorm rows of x (fp32) -> h (bf16). One wave per row.
// ---------------------------------------------------------------------------
__global__ __launch_bounds__(256) void k_rms(const float* __restrict__ x,
                                             __hip_bfloat16* __restrict__ h) {
    const int wave = threadIdx.x >> 6;
    const int lane = threadIdx.x & 63;
    const size_t row = (size_t)blockIdx.x * 4 + wave;

    const float4* xr = (const float4*)(x + row * H);
    float4 v[4];
    float ss = 0.f;
#pragma unroll
    for (int i = 0; i < 4; ++i) {
        v[i] = xr[lane + 64 * i];
        ss += v[i].x * v[i].x + v[i].y * v[i].y + v[i].z * v[i].z + v[i].w * v[i].w;
    }
#pragma unroll
    for (int o = 1; o < 64; o <<= 1) ss += __shfl_xor(ss, o);
    const float sc = rsqrtf(ss * (1.0f / H) + 1e-6f);

    ushort4* hr = (ushort4*)(h + row * H);
#pragma unroll
    for (int i = 0; i < 4; ++i) {
        ushort4 o4;
        o4.x = f2bf(v[i].x * sc);
        o4.y = f2bf(v[i].y * sc);
        o4.z = f2bf(v[i].z * sc);
        o4.w = f2bf(v[i].w * sc);
        hr[lane + 64 * i] = o4;
    }
}

// ---------------------------------------------------------------------------
// Kernel 2: build transposed fused weight Bt[n][k] = bf16((1+lnw[k]) * W[k][n])
// ---------------------------------------------------------------------------
__global__ __launch_bounds__(256) void k_wprep(const float* __restrict__ wq,
                                               const float* __restrict__ wk,
                                               const float* __restrict__ wv,
                                               const float* __restrict__ lnw,
                                               __hip_bfloat16* __restrict__ Bt) {
    const int idx = blockIdx.x * 256 + threadIdx.x;  // idx = n*1024 + k
    const int n = idx >> 10;
    const int k = idx & 1023;
    const float s = 1.0f + lnw[k];
    float w;
    if (n < 1024)       w = wq[k * 1024 + n];
    else if (n < 1152)  w = wk[k * 128 + (n - 1024)];
    else                w = wv[k * 128 + (n - 1152)];
    Bt[idx] = __float2bfloat16(s * w);
}

// ---------------------------------------------------------------------------
// Kernel 3: GEMM out[M][1280] = h[M][1024] @ Bt^T.
// 256x256 tile, BK=64, 8 waves (2M x 4N), 512 threads, ring-2 LDS 128 KiB,
// T2 XOR swizzle (both-sides), counted vmcnt(8).
// NEW (R3): 4 barrier-pinned phases per K-tile, 16 MFMA each, T5 setprio.
//   P0: vm(8);bar; read a0h0+b0; bar; lgkm0; prio1; 16 MFMA; prio0
//   P1: read a0h1;              bar; lgkm0; prio1; 16 MFMA; prio0
//   P2: read a1h0+b1;           bar; lgkm0; prio1; 16 MFMA; prio0
//   P3: read a1h1; lgkm0; bar(all reads of tile done); STAGE(kt+2);
//       prio1; 16 MFMA; prio0
// ---------------------------------------------------------------------------
__global__ __launch_bounds__(512, 2) void k_gemm(const __hip_bfloat16* __restrict__ A,
                                                 const __hip_bfloat16* __restrict__ Bt,
                                                 float* __restrict__ out, int rows) {
    __shared__ __align__(16) char smem[131072];  // 2 bufs x (A 32KB | B 32KB)

    const int tid = threadIdx.x;
    const int lane = tid & 63;
    const int wid = tid >> 6;
    const int wm = wid >> 2;   // 0..1
    const int wn = wid & 3;    // 0..3

    // bijective XCD chunk swizzle, nt fastest (A-strip sharers on one XCD L2)
    const int nwg = gridDim.x;
    const int q8 = nwg >> 3, r8 = nwg & 7;
    const int xcd = blockIdx.x & 7, rank = blockIdx.x >> 3;
    const int wg = (xcd < r8 ? xcd * (q8 + 1) : r8 * (q8 + 1) + (xcd - r8) * q8) + rank;
    const int nt = wg % (NTOT / BN);   // 0..4
    const int mt = wg / (NTOT / BN);
    const size_t m0 = (size_t)mt * BM;

    // staging: thread t covers LDS row t/8 (+j*64), 16B at (t%8)*16, source
    // col pre-swizzled by ((row&7)<<4) (both-sides involution, rule 21)
    const int cswz = ((tid & 7) * 16) ^ (((tid >> 3) & 7) << 4);
    const char* aG = (const char*)A + (m0 + (tid >> 3)) * (size_t)(H * 2) + cswz;
    const char* bG = (const char*)Bt + ((size_t)nt * BN + (tid >> 3)) * (size_t)(H * 2) + cswz;

#define STAGE(buf, kt)                                                        \
    {                                                                         \
        const char* as_ = aG + (size_t)(kt) * (BK * 2);                       \
        const char* bs_ = bG + (size_t)(kt) * (BK * 2);                       \
        char* ld_ = smem + (buf) * 65536 + tid * 16;                          \
        _Pragma("unroll") for (int j = 0; j < 4; ++j)                         \
            GLOAD_LDS16(as_ + (size_t)j * 64 * (H * 2), ld_ + j * 8192);      \
        _Pragma("unroll") for (int j = 0; j < 4; ++j)                         \
            GLOAD_LDS16(bs_ + (size_t)j * 64 * (H * 2), ld_ + 32768 + j * 8192); \
    }

    // fragment read addressing (swizzled)
    const int rowA = wm * 128 + (lane & 15);
    const int rowB = wn * 64 + (lane & 15);
    const int xm = (lane & 7) << 4;
    const int c0 = (((lane >> 4) * 16)) ^ xm;        // kk=0 col bytes
    const int c1 = (64 + ((lane >> 4) * 16)) ^ xm;   // kk=1 col bytes

    f32x4 acc[8][4] = {};

    STAGE(0, 0);
    STAGE(1, 1);

#define MFMA4x4(AF, BF, MIOFF)                                                \
    _Pragma("unroll") for (int mi = 0; mi < 4; ++mi)                          \
        _Pragma("unroll") for (int ni = 0; ni < 4; ++ni)                      \
            acc[(MIOFF) + mi][ni] = __builtin_amdgcn_mfma_f32_16x16x32_bf16(  \
                AF[mi], BF[ni], acc[(MIOFF) + mi][ni], 0, 0, 0);

#define TILE(cur, kt, DOSTAGE, VMSTR)                                         \
    {                                                                         \
        const char* aLb = smem + (cur) * 65536;                               \
        const char* bLb = aLb + 32768;                                        \
        /* P0 */                                                              \
        asm volatile("s_waitcnt vmcnt(" VMSTR ")" ::: "memory");              \
        __builtin_amdgcn_s_barrier();                                         \
        bf16x8 a0h0[4], b0[4];                                                \
        _Pragma("unroll") for (int mi = 0; mi < 4; ++mi)                      \
            a0h0[mi] = *(const bf16x8*)(aLb + (rowA + mi * 16) * 128 + c0);   \
        _Pragma("unroll") for (int ni = 0; ni < 4; ++ni)                      \
            b0[ni] = *(const bf16x8*)(bLb + (rowB + ni * 16) * 128 + c0);     \
        __builtin_amdgcn_s_barrier();                                         \
        asm volatile("s_waitcnt lgkmcnt(0)" ::: "memory");                    \
        __builtin_amdgcn_s_setprio(1);                                        \
        MFMA4x4(a0h0, b0, 0);                                                 \
        __builtin_amdgcn_s_setprio(0);                                        \
        /* P1 */                                                              \
        bf16x8 a0h1[4];                                                       \
        _Pragma("unroll") for (int mi = 0; mi < 4; ++mi)                      \
            a0h1[mi] = *(const bf16x8*)(aLb + (rowA + 64 + mi * 16) * 128 + c0); \
        __builtin_amdgcn_s_barrier();                                         \
        asm volatile("s_waitcnt lgkmcnt(0)" ::: "memory");                    \
        __builtin_amdgcn_s_setprio(1);                                        \
        MFMA4x4(a0h1, b0, 4);                                                 \
        __builtin_amdgcn_s_setprio(0);                                        \
        /* P2 */                                                              \
        bf16x8 a1h0[4], b1[4];                                                \
        _Pragma("unroll") for (int mi = 0; mi < 4; ++mi)                      \
            a1h0[mi] = *(const bf16x8*)(aLb + (rowA + mi * 16) * 128 + c1);   \
        _Pragma("unroll") for (int ni = 0; ni < 4; ++ni)                      \
            b1[ni] = *(const bf16x8*)(bLb + (rowB + ni * 16) * 128 + c1);     \
        __builtin_amdgcn_s_barrier();                                         \
        asm volatile("s_waitcnt lgkmcnt(0)" ::: "memory");                    \
        __builtin_amdgcn_s_setprio(1);                                        \
        MFMA4x4(a1h0, b1, 0);                                                 \
        __builtin_amdgcn_s_setprio(0);                                        \
        /* P3 */                                                              \
        bf16x8 a1h1[4];                                                       \
        _Pragma("unroll") for (int mi = 0; mi < 4; ++mi)                      \
            a1h1[mi] = *(const bf16x8*)(aLb + (rowA + 64 + mi * 16) * 128 + c1); \
        asm volatile("s_waitcnt lgkmcnt(0)" ::: "memory");                    \
        __builtin_amdgcn_s_barrier();                                         \
        if (DOSTAGE) STAGE(cur, (kt) + 2);                                    \
        __builtin_amdgcn_s_setprio(1);                                        \
        MFMA4x4(a1h1, b1, 4);                                                 \
        __builtin_amdgcn_s_setprio(0);                                        \
    }

    for (int kt = 0; kt < NKT - 2; kt += 2) {
        TILE(0, kt, true, "8");
        TILE(1, kt + 1, true, "8");
    }
    TILE(0, NKT - 2, false, "8");
    TILE(1, NKT - 1, false, "0");

    // epilogue: split q/k/v regions (wn*64 chunks never straddle boundaries)
    const size_t QSZ = (size_t)rows * 1024;
    const size_t KSZ = (size_t)rows * 128;
    const int colg0 = nt * BN + wn * 64;
    float* op;
    int ldc, cb0;
    if (colg0 < 1024)      { op = out;             ldc = 1024; cb0 = colg0; }
    else if (colg0 < 1152) { op = out + QSZ;       ldc = 128;  cb0 = colg0 - 1024; }
    else                   { op = out + QSZ + KSZ; ldc = 128;  cb0 = colg0 - 1152; }

    const size_t r0 = m0 + wm * 128 + ((lane >> 4) * 4);
    const int cc0 = cb0 + (lane & 15);
#pragma unroll
    for (int mi = 0; mi < 8; ++mi)
#pragma unroll
        for (int ni = 0; ni < 4; ++ni)
#pragma unroll
            for (int r = 0; r < 4; ++r)
                op[(r0 + mi * 16 + r) * (size_t)ldc + cc0 + ni * 16] = acc[mi][ni][r];
}

// ---------------------------------------------------------------------------
extern "C" void kernel_launch(void* const* d_in, const int* in_sizes, int n_in,
                              void* d_out, int out_size, void* d_ws, size_t ws_size,
                              hipStream_t stream) {
    const float* x   = (const float*)d_in[0];
    const float* lnw = (const float*)d_in[1];
    const float* wq  = (const float*)d_in[2];
    const float* wk  = (const float*)d_in[3];
    const float* wv  = (const float*)d_in[4];
    float* out = (float*)d_out;

    const int rows = in_sizes[0] / H;  // B*S = 32768

    __hip_bfloat16* Bt = (__hip_bfloat16*)d_ws;                               // 2.62 MB
    __hip_bfloat16* h  = (__hip_bfloat16*)((char*)d_ws + (size_t)NTOT * H * 2);

    k_wprep<<<NTOT * H / 256, 256, 0, stream>>>(wq, wk, wv, lnw, Bt);
    k_rms<<<rows / 4, 256, 0, stream>>>(x, h);
    k_gemm<<<(rows / BM) * (NTOT / BN), 512, 0, stream>>>(h, Bt, out, rows);
}

// Round 4
// 154.758 us; speedup vs baseline: 1.0119x; 1.0119x over previous
//
#include <hip/hip_runtime.h>
#include <hip/hip_bf16.h>

typedef __attribute__((ext_vector_type(4))) float f32x4;
typedef __attribute__((ext_vector_type(8))) short bf16x8;

#define H 1024        // hidden / K
#define NTOT 1280     // nq*64 + nkv*64*2
#define BM 256
#define BN 256
#define BK 64
#define NKT (H / BK)  // 16 K-tiles

static __device__ __forceinline__ unsigned short f2bf(float f) {
    __hip_bfloat16 b = __float2bfloat16(f);
    return __builtin_bit_cast(unsigned short, b);
}

#define GLOAD_LDS16(g, l)                                                     \
    __builtin_amdgcn_global_load_lds(                                         \
        (const __attribute__((address_space(1))) void*)(g),                   \
        (__attribute__((address_space(3))) void*)(l), 16, 0, 0)

// ---------------------------------------------------------------------------
// Kernel 1: RMSNorm rows of x (fp32) -> h (bf16). One wave per row.
// ---------------------------------------------------------------------------
__global__ __launch_bounds__(256) void k_rms(const float* __restrict__ x,
                                             __hip_bfloat16* __restrict__ h) {
    const int wave = threadIdx.x >> 6;
    const int lane = threadIdx.x & 63;
    const size_t row = (size_t)blockIdx.x * 4 + wave;

    const float4* xr = (const float4*)(x + row * H);
    float4 v[4];
    float ss = 0.f;
#pragma unroll
    for (int i = 0; i < 4; ++i) {
        v[i] = xr[lane + 64 * i];
        ss += v[i].x * v[i].x + v[i].y * v[i].y + v[i].z * v[i].z + v[i].w * v[i].w;
    }
#pragma unroll
    for (int o = 1; o < 64; o <<= 1) ss += __shfl_xor(ss, o);
    const float sc = rsqrtf(ss * (1.0f / H) + 1e-6f);

    ushort4* hr = (ushort4*)(h + row * H);
#pragma unroll
    for (int i = 0; i < 4; ++i) {
        ushort4 o4;
        o4.x = f2bf(v[i].x * sc);
        o4.y = f2bf(v[i].y * sc);
        o4.z = f2bf(v[i].z * sc);
        o4.w = f2bf(v[i].w * sc);
        hr[lane + 64 * i] = o4;
    }
}

// ---------------------------------------------------------------------------
// Kernel 2: build transposed fused weight Bt[n][k] = bf16((1+lnw[k]) * W[k][n])
// ---------------------------------------------------------------------------
__global__ __launch_bounds__(256) void k_wprep(const float* __restrict__ wq,
                                               const float* __restrict__ wk,
                                               const float* __restrict__ wv,
                                               const float* __restrict__ lnw,
                                               __hip_bfloat16* __restrict__ Bt) {
    const int idx = blockIdx.x * 256 + threadIdx.x;  // idx = n*1024 + k
    const int n = idx >> 10;
    const int k = idx & 1023;
    const float s = 1.0f + lnw[k];
    float w;
    if (n < 1024)       w = wq[k * 1024 + n];
    else if (n < 1152)  w = wk[k * 128 + (n - 1024)];
    else                w = wv[k * 128 + (n - 1152)];
    Bt[idx] = __float2bfloat16(s * w);
}

// ---------------------------------------------------------------------------
// Kernel 3: GEMM out[M][1280] = h[M][1024] @ Bt^T.
// 256x256 tile, BK=64, 8 waves (2M x 4N), 512 threads, ring-2 LDS 128 KiB,
// T2 XOR swizzle (both-sides), XCD chunking.
// R4: faithful m201 quadrant-phase schedule. Per K-tile, 4 phases x 16 MFMA:
//   P1 (q00): 12 reads (A-h0 both kk, B-h0 both kk); lgkm(8); BAR; lgkm0;
//             prio1; MFMA acc[0..3][0..1]; prio0; BAR
//   P2 (q01): 2 gloads (A-q0,q2 of kt+2); 4 reads (B-h1); BAR; lgkm0;
//             prio1; MFMA acc[0..3][2..3]; prio0; BAR
//   P3 (q10): 2 gloads (B-q0,q1); 8 reads (A-h1); BAR; lgkm0;
//             prio1; MFMA acc[4..7][0..1]; prio0; BAR
//   P4 (q11): 4 gloads (A-q1,q3, B-q2,q3); prio1; MFMA acc[4..7][2..3]; prio0;
//             vmcnt(8); BAR
// Staging of kt+2 dribbles into the region the barrier just retired
// (A-h0 after P1's end-bar, B after P2's end-bar, A-h1 after P3's end-bar).
// vmcnt(8) at tile seam = wait for next tile's 8 loads (oldest), keep 8 newest
// in flight. Never drains to 0 in the main loop.
// ---------------------------------------------------------------------------
__global__ __launch_bounds__(512, 2) void k_gemm(const __hip_bfloat16* __restrict__ A,
                                                 const __hip_bfloat16* __restrict__ Bt,
                                                 float* __restrict__ out, int rows) {
    __shared__ __align__(16) char smem[131072];  // 2 bufs x (A 32KB | B 32KB)

    const int tid = threadIdx.x;
    const int lane = tid & 63;
    const int wid = tid >> 6;
    const int wm = wid >> 2;   // 0..1
    const int wn = wid & 3;    // 0..3

    // bijective XCD chunk swizzle, nt fastest (A-strip sharers on one XCD L2)
    const int nwg = gridDim.x;
    const int q8 = nwg >> 3, r8 = nwg & 7;
    const int xcd = blockIdx.x & 7, rank = blockIdx.x >> 3;
    const int wg = (xcd < r8 ? xcd * (q8 + 1) : r8 * (q8 + 1) + (xcd - r8) * q8) + rank;
    const int nt = wg % (NTOT / BN);   // 0..4
    const int mt = wg / (NTOT / BN);
    const size_t m0 = (size_t)mt * BM;

    // staging: thread t covers LDS row t/8 (+q*64), 16B at (t%8)*16, source
    // col pre-swizzled by ((row&7)<<4) (both-sides involution, rule 21)
    const int cswz = ((tid & 7) * 16) ^ (((tid >> 3) & 7) << 4);
    const char* aG = (const char*)A + (m0 + (tid >> 3)) * (size_t)(H * 2) + cswz;
    const char* bG = (const char*)Bt + ((size_t)nt * BN + (tid >> 3)) * (size_t)(H * 2) + cswz;

    // single-quarter stages (quarter q = 64 rows)
#define STAGE_A(buf, kt, q)                                                   \
    GLOAD_LDS16(aG + (size_t)(kt) * (BK * 2) + (size_t)(q) * 64 * (H * 2),    \
                smem + (buf) * 65536 + (q) * 8192 + tid * 16)
#define STAGE_B(buf, kt, q)                                                   \
    GLOAD_LDS16(bG + (size_t)(kt) * (BK * 2) + (size_t)(q) * 64 * (H * 2),    \
                smem + (buf) * 65536 + 32768 + (q) * 8192 + tid * 16)

    // fragment read addressing (swizzled)
    const int rowA = wm * 128 + (lane & 15);       // + h*64 + mi*16
    const int rowB = wn * 64 + (lane & 15);        // + nh*32 + ni*16
    const int xm = (lane & 7) << 4;
    const int c0 = (((lane >> 4) * 16)) ^ xm;      // kk=0 col bytes
    const int c1 = (64 + ((lane >> 4) * 16)) ^ xm; // kk=1 col bytes

    f32x4 acc[8][4] = {};

    // prologue: full stage of tiles 0 and 1
#pragma unroll
    for (int q = 0; q < 4; ++q) { STAGE_A(0, 0, q); STAGE_B(0, 0, q); }
#pragma unroll
    for (int q = 0; q < 4; ++q) { STAGE_A(1, 1, q); STAGE_B(1, 1, q); }
    asm volatile("s_waitcnt vmcnt(8)" ::: "memory");
    __builtin_amdgcn_s_barrier();

#define MFMA16(AK0, AK1, BK0, BK1, MIOFF, NIOFF)                              \
    _Pragma("unroll") for (int mi = 0; mi < 4; ++mi)                          \
        _Pragma("unroll") for (int ni = 0; ni < 2; ++ni)                      \
            acc[(MIOFF) + mi][(NIOFF) + ni] =                                 \
                __builtin_amdgcn_mfma_f32_16x16x32_bf16(                      \
                    AK0[mi], BK0[ni], acc[(MIOFF) + mi][(NIOFF) + ni], 0, 0, 0); \
    _Pragma("unroll") for (int mi = 0; mi < 4; ++mi)                          \
        _Pragma("unroll") for (int ni = 0; ni < 2; ++ni)                      \
            acc[(MIOFF) + mi][(NIOFF) + ni] =                                 \
                __builtin_amdgcn_mfma_f32_16x16x32_bf16(                      \
                    AK1[mi], BK1[ni], acc[(MIOFF) + mi][(NIOFF) + ni], 0, 0, 0);

#define TILE(cur, kt, DOSTAGE, VMSTR)                                         \
    {                                                                         \
        const char* aLb = smem + (cur) * 65536;                               \
        const char* bLb = aLb + 32768;                                        \
        /* ---- P1 (q00): 12 reads ---- */                                    \
        bf16x8 a0k0[4], a0k1[4], b0k0[2], b0k1[2];                            \
        _Pragma("unroll") for (int mi = 0; mi < 4; ++mi) {                    \
            a0k0[mi] = *(const bf16x8*)(aLb + (rowA + mi * 16) * 128 + c0);   \
            a0k1[mi] = *(const bf16x8*)(aLb + (rowA + mi * 16) * 128 + c1);   \
        }                                                                     \
        _Pragma("unroll") for (int ni = 0; ni < 2; ++ni) {                    \
            b0k0[ni] = *(const bf16x8*)(bLb + (rowB + ni * 16) * 128 + c0);   \
            b0k1[ni] = *(const bf16x8*)(bLb + (rowB + ni * 16) * 128 + c1);   \
        }                                                                     \
        asm volatile("s_waitcnt lgkmcnt(8)" ::: "memory");                    \
        __builtin_amdgcn_s_barrier();                                         \
        asm volatile("s_waitcnt lgkmcnt(0)" ::: "memory");                    \
        __builtin_amdgcn_s_setprio(1);                                        \
        MFMA16(a0k0, a0k1, b0k0, b0k1, 0, 0);                                 \
        __builtin_amdgcn_s_setprio(0);                                        \
        __builtin_amdgcn_s_barrier();                                         \
        /* ---- P2 (q01): stage A-h0 quarters of kt+2; 4 reads ---- */        \
        if (DOSTAGE) { STAGE_A(cur, (kt) + 2, 0); STAGE_A(cur, (kt) + 2, 2); } \
        bf16x8 b1k0[2], b1k1[2];                                              \
        _Pragma("unroll") for (int ni = 0; ni < 2; ++ni) {                    \
            b1k0[ni] = *(const bf16x8*)(bLb + (rowB + 32 + ni * 16) * 128 + c0); \
            b1k1[ni] = *(const bf16x8*)(bLb + (rowB + 32 + ni * 16) * 128 + c1); \
        }                                                                     \
        __builtin_amdgcn_s_barrier();                                         \
        asm volatile("s_waitcnt lgkmcnt(0)" ::: "memory");                    \
        __builtin_amdgcn_s_setprio(1);                                        \
        MFMA16(a0k0, a0k1, b1k0, b1k1, 0, 2);                                 \
        __builtin_amdgcn_s_setprio(0);                                        \
        __builtin_amdgcn_s_barrier();                                         \
        /* ---- P3 (q10): stage B quarters 0,1; 8 reads ---- */               \
        if (DOSTAGE) { STAGE_B(cur, (kt) + 2, 0); STAGE_B(cur, (kt) + 2, 1); } \
        bf16x8 a1k0[4], a1k1[4];                                              \
        _Pragma("unroll") for (int mi = 0; mi < 4; ++mi) {                    \
            a1k0[mi] = *(const bf16x8*)(aLb + (rowA + 64 + mi * 16) * 128 + c0); \
            a1k1[mi] = *(const bf16x8*)(aLb + (rowA + 64 + mi * 16) * 128 + c1); \
        }                                                                     \
        __builtin_amdgcn_s_barrier();                                         \
        asm volatile("s_waitcnt lgkmcnt(0)" ::: "memory");                    \
        __builtin_amdgcn_s_setprio(1);                                        \
        MFMA16(a1k0, a1k1, b0k0, b0k1, 4, 0);                                 \
        __builtin_amdgcn_s_setprio(0);                                        \
        __builtin_amdgcn_s_barrier();                                         \
        /* ---- P4 (q11): stage A-h1 + B quarters 2,3; 0 reads ---- */        \
        if (DOSTAGE) { STAGE_A(cur, (kt) + 2, 1); STAGE_A(cur, (kt) + 2, 3);  \
                       STAGE_B(cur, (kt) + 2, 2); STAGE_B(cur, (kt) + 2, 3); } \
        __builtin_amdgcn_s_setprio(1);                                        \
        MFMA16(a1k0, a1k1, b1k0, b1k1, 4, 2);                                 \
        __builtin_amdgcn_s_setprio(0);                                        \
        asm volatile("s_waitcnt vmcnt(" VMSTR ")" ::: "memory");              \
        __builtin_amdgcn_s_barrier();                                         \
    }

    for (int kt = 0; kt < NKT - 2; kt += 2) {
        TILE(0, kt, 1, "8");
        TILE(1, kt + 1, 1, "8");
    }
    TILE(0, NKT - 2, 0, "0");
    TILE(1, NKT - 1, 0, "0");

    // epilogue: split q/k/v regions (wn*64 chunks never straddle boundaries)
    const size_t QSZ = (size_t)rows * 1024;
    const size_t KSZ = (size_t)rows * 128;
    const int colg0 = nt * BN + wn * 64;
    float* op;
    int ldc, cb0;
    if (colg0 < 1024)      { op = out;             ldc = 1024; cb0 = colg0; }
    else if (colg0 < 1152) { op = out + QSZ;       ldc = 128;  cb0 = colg0 - 1024; }
    else                   { op = out + QSZ + KSZ; ldc = 128;  cb0 = colg0 - 1152; }

    const size_t r0 = m0 + wm * 128 + ((lane >> 4) * 4);
    const int cc0 = cb0 + (lane & 15);
#pragma unroll
    for (int mi = 0; mi < 8; ++mi)
#pragma unroll
        for (int ni = 0; ni < 4; ++ni)
#pragma unroll
            for (int r = 0; r < 4; ++r)
                op[(r0 + mi * 16 + r) * (size_t)ldc + cc0 + ni * 16] = acc[mi][ni][r];
}

// ---------------------------------------------------------------------------
extern "C" void kernel_launch(void* const* d_in, const int* in_sizes, int n_in,
                              void* d_out, int out_size, void* d_ws, size_t ws_size,
                              hipStream_t stream) {
    const float* x   = (const float*)d_in[0];
    const float* lnw = (const float*)d_in[1];
    const float* wq  = (const float*)d_in[2];
    const float* wk  = (const float*)d_in[3];
    const float* wv  = (const float*)d_in[4];
    float* out = (float*)d_out;

    const int rows = in_sizes[0] / H;  // B*S = 32768

    __hip_bfloat16* Bt = (__hip_bfloat16*)d_ws;                               // 2.62 MB
    __hip_bfloat16* h  = (__hip_bfloat16*)((char*)d_ws + (size_t)NTOT * H * 2);

    k_wprep<<<NTOT * H / 256, 256, 0, stream>>>(wq, wk, wv, lnw, Bt);
    k_rms<<<rows / 4, 256, 0, stream>>>(x, h);
    k_gemm<<<(rows / BM) * (NTOT / BN), 512, 0, stream>>>(h, Bt, out, rows);
}